// Round 8
// baseline (6572.487 us; speedup 1.0000x reference)
//
#include <hip/hip_runtime.h>
#include <math.h>

#define NTOK 32768
#define DIM 512
#define KC 8192

// ---- MFMA pipeline geometry ----
#define TBM 128              // token tile
#define TBN 128              // code tile
#define HSTEPS 16            // k-chunks (512 / 32)
#define PSTEP 4096           // u16 per plane-chunk per 128-row tile (128 rows x 32 halves = 8 KB)

typedef unsigned short u16;
typedef _Float16 half8 __attribute__((ext_vector_type(8)));
typedef float f32x4 __attribute__((ext_vector_type(4)));

// ---- async global->LDS, 16B per lane (dest = wave-uniform base + lane*16) ----
__device__ __forceinline__ void gload16(const void* g, void* l) {
    __builtin_amdgcn_global_load_lds(
        (const __attribute__((address_space(1))) unsigned int*)(void*)g,
        (__attribute__((address_space(3))) unsigned int*)l, 16, 0, 0);
}

// ================= small kernels =================
__global__ __launch_bounds__(256) void c2_kernel(const float* __restrict__ W,
                                                 float* __restrict__ c2) {
    int wid = threadIdx.x >> 6;
    int lane = threadIdx.x & 63;
    int row = blockIdx.x * 4 + wid;
    const float* wr = W + (size_t)row * DIM;
    float s = 0.f;
#pragma unroll
    for (int q = 0; q < 2; ++q) {
        float4 v = *(const float4*)(wr + q * 256 + lane * 4);
        s += v.x * v.x + v.y * v.y + v.z * v.z + v.w * v.w;
    }
#pragma unroll
    for (int off = 32; off > 0; off >>= 1) s += __shfl_down(s, off);
    if (lane == 0) c2[row] = s;
}

__global__ __launch_bounds__(256) void loss_kernel(const float* __restrict__ partials,
                                                   float* __restrict__ lossp) {
    __shared__ float red[256];
    float s = 0.f;
    for (int idx = threadIdx.x; idx < NTOK / 4; idx += 256) s += partials[idx];
    red[threadIdx.x] = s;
    __syncthreads();
    for (int off = 128; off > 0; off >>= 1) {
        if (threadIdx.x < off) red[threadIdx.x] += red[threadIdx.x + off];
        __syncthreads();
    }
    if (threadIdx.x == 0) lossp[0] = 1.25f * red[0] / (float)NTOK;
}

__global__ void init_keys_kernel(unsigned long long* keys) {
    keys[blockIdx.x * 256 + threadIdx.x] = ~0ull;
}

// ================= split: fp32 -> fp16 hi/lo planes =================
// Per matrix: tiles of 128 rows; per tile 32 plane-steps (0-15 hi, 16-31 lo);
// per step: 128 rows x 32 halves (64 B/row = 4 chunks of 16 B).
// SWZ=1 (x / LDS path): chunk c stored at slot c ^ ((Rl>>1)&3) -> conflict-free
// ds_read_b128 after LINEAR global_load_lds staging.
// SWZ=0 (W / direct-to-register path): linear slots.
template <int SWZ>
__global__ __launch_bounds__(256) void split_kernel(const float* __restrict__ src,
                                                    u16* __restrict__ dst) {
    int lane = threadIdx.x & 63;
    int wid = threadIdx.x >> 6;
    int row = blockIdx.x * 64 + lane;
    int s = blockIdx.y * 4 + wid;          // hi step 0..15
    const float* p = src + (size_t)row * DIM + s * 32;
    int tile = row >> 7, Rl = row & 127, swz = (Rl >> 1) & 3;
    u16* baseH = dst + ((size_t)(tile * 32 + s) * 128 + Rl) * 32;
    u16* baseL = baseH + (size_t)16 * PSTEP;
#pragma unroll
    for (int c = 0; c < 4; ++c) {
        float4 va = ((const float4*)p)[c * 2];
        float4 vb = ((const float4*)p)[c * 2 + 1];
        float f[8] = {va.x, va.y, va.z, va.w, vb.x, vb.y, vb.z, vb.w};
        unsigned H[4], L[4];
#pragma unroll
        for (int j = 0; j < 4; ++j) {
            _Float16 h0 = (_Float16)f[2 * j];
            _Float16 g0 = (_Float16)(f[2 * j] - (float)h0);
            _Float16 h1 = (_Float16)f[2 * j + 1];
            _Float16 g1 = (_Float16)(f[2 * j + 1] - (float)h1);
            H[j] = (unsigned)__builtin_bit_cast(u16, h0) |
                   ((unsigned)__builtin_bit_cast(u16, h1) << 16);
            L[j] = (unsigned)__builtin_bit_cast(u16, g0) |
                   ((unsigned)__builtin_bit_cast(u16, g1) << 16);
        }
        int slot = (SWZ ? (c ^ swz) : c) * 8;
        *(uint4*)(baseH + slot) = uint4{H[0], H[1], H[2], H[3]};
        *(uint4*)(baseL + slot) = uint4{L[0], L[1], L[2], L[3]};
    }
}

// ================= fused GEMM + argmin: A via LDS (32 KB), B direct-to-reg =================
// 32 KB LDS -> 5 blocks/CU (20 waves/CU): latency hiding via real concurrency.
// B fragments double-buffered in named register sets (no runtime indexing).
#define CHUNK(c, PAR, CURH, CURL, NXTH, NXTL)                                        \
    {                                                                                \
        asm volatile("s_waitcnt vmcnt(0)" ::: "memory");                             \
        __builtin_amdgcn_s_barrier();                                                \
        __builtin_amdgcn_sched_barrier(0);                                           \
        if ((c) + 1 < HSTEPS) {                                                      \
            const u16* ah = gA + (size_t)((c) + 1) * PSTEP;                          \
            const u16* al = ah + 16 * PSTEP;                                         \
            u16* dah = AH[(PAR) ^ 1];                                                \
            u16* dal = AL[(PAR) ^ 1];                                                \
            gload16(ah + wo + lo8, dah + wo);                                        \
            gload16(ah + wo + 512 + lo8, dah + wo + 512);                            \
            gload16(al + wo + lo8, dal + wo);                                        \
            gload16(al + wo + 512 + lo8, dal + wo + 512);                            \
            const u16* bh = gB + (size_t)((c) + 1) * PSTEP;                          \
            const u16* bl = bh + 16 * PSTEP;                                         \
            _Pragma("unroll")                                                        \
            for (int n = 0; n < 4; ++n) {                                            \
                NXTH[n] = *(const half8*)(bh + boff + n * 512);                      \
                NXTL[n] = *(const half8*)(bl + boff + n * 512);                      \
            }                                                                        \
        }                                                                            \
        half8 ahv[4], alv[4];                                                        \
        _Pragma("unroll")                                                            \
        for (int m = 0; m < 4; ++m)                                                  \
            ahv[m] = *(const half8*)(AH[PAR] + arow + m * 512 + soff);               \
        __builtin_amdgcn_s_setprio(1);                                               \
        _Pragma("unroll")                                                            \
        for (int m = 0; m < 4; ++m)                                                  \
            _Pragma("unroll")                                                        \
            for (int n = 0; n < 4; ++n)                                              \
                acc[m][n] = __builtin_amdgcn_mfma_f32_16x16x32_f16(ahv[m], CURH[n], acc[m][n], 0, 0, 0); \
        __builtin_amdgcn_s_setprio(0);                                               \
        _Pragma("unroll")                                                            \
        for (int m = 0; m < 4; ++m)                                                  \
            alv[m] = *(const half8*)(AL[PAR] + arow + m * 512 + soff);               \
        __builtin_amdgcn_s_setprio(1);                                               \
        _Pragma("unroll")                                                            \
        for (int m = 0; m < 4; ++m)                                                  \
            _Pragma("unroll")                                                        \
            for (int n = 0; n < 4; ++n)                                              \
                acc[m][n] = __builtin_amdgcn_mfma_f32_16x16x32_f16(alv[m], CURH[n], acc[m][n], 0, 0, 0); \
        _Pragma("unroll")                                                            \
        for (int m = 0; m < 4; ++m)                                                  \
            _Pragma("unroll")                                                        \
            for (int n = 0; n < 4; ++n)                                              \
                acc[m][n] = __builtin_amdgcn_mfma_f32_16x16x32_f16(ahv[m], CURL[n], acc[m][n], 0, 0, 0); \
        __builtin_amdgcn_s_setprio(0);                                               \
    }

__global__ __launch_bounds__(256, 5) void argmin_mfma_kernel(
    const u16* __restrict__ xscr, const u16* __restrict__ wscr,
    const float* __restrict__ c2, unsigned long long* __restrict__ keys) {
    __shared__ __align__(16) u16 AH[2][PSTEP];
    __shared__ __align__(16) u16 AL[2][PSTEP];   // total 32 KB -> 5 blocks/CU

    // XCD-aware swizzle (16384 % 8 == 0 -> bijective)
    int cpx = (int)gridDim.x >> 3;
    int bid = (int)blockIdx.x;
    int wg = (bid & 7) * cpx + (bid >> 3);
    int tcol = wg & 63;    // 64 code tiles of 128
    int trow = wg >> 6;    // 256 token tiles of 128

    const int tid = threadIdx.x;
    const int lane = tid & 63;
    const int w = tid >> 6;
    const int wr = w >> 1;           // M half (64 rows)
    const int wc = w & 1;            // N half (64 cols)

    const u16* gA = xscr + (size_t)trow * (32 * PSTEP);   // [0..15]=hi, [16..31]=lo
    const u16* gB = wscr + (size_t)tcol * (32 * PSTEP);   // linear layout

    const int l15 = lane & 15, q = lane >> 4;
    float c2v[4];
    const int colbase = tcol * 128 + wc * 64 + l15;
#pragma unroll
    for (int n = 0; n < 4; ++n) c2v[n] = c2[colbase + n * 16];

    f32x4 acc[4][4];
#pragma unroll
    for (int m = 0; m < 4; ++m)
#pragma unroll
        for (int n = 0; n < 4; ++n) acc[m][n] = f32x4{0.f, 0.f, 0.f, 0.f};

    // A LDS read offsets (u16 units), conflict-free via pre-swizzled source.
    const int swz = (l15 >> 1) & 3;
    const int soff = (q ^ swz) * 8;
    const int arow = (wr * 64 + l15) * 32;   // + m*512
    // B direct-load offset (linear scratch, u16 units): row*32 + q*8, rows n*16 apart.
    const int boff = (wc * 64 + l15) * 32 + q * 8;
    const int wo = w * 1024;         // wave's 2 KB slice of each 8 KB plane (u16)
    const int lo8 = lane * 8;        // lane's 16 B (global side only)

    half8 bhP[4], blP[4], bhQ[4], blQ[4];

    // prologue: stage A chunk 0 into buffer 0; load B chunk 0 into P regs
    {
        const u16* ah = gA;
        const u16* al = gA + 16 * PSTEP;
        gload16(ah + wo + lo8, AH[0] + wo);
        gload16(ah + wo + 512 + lo8, AH[0] + wo + 512);
        gload16(al + wo + lo8, AL[0] + wo);
        gload16(al + wo + 512 + lo8, AL[0] + wo + 512);
        const u16* bh = gB;
        const u16* bl = gB + 16 * PSTEP;
#pragma unroll
        for (int n = 0; n < 4; ++n) {
            bhP[n] = *(const half8*)(bh + boff + n * 512);
            blP[n] = *(const half8*)(bl + boff + n * 512);
        }
    }

    for (int c = 0; c < HSTEPS; c += 2) {
        CHUNK(c, 0, bhP, blP, bhQ, blQ);
        CHUNK(c + 1, 1, bhQ, blQ, bhP, blP);
    }

    // ---- epilogue: scores + argmin; block-level key reduce in LDS ----
    unsigned long long* kbuf = (unsigned long long*)&AH[0][0];  // [2][128]; AH[0] last read chunk 14
#pragma unroll
    for (int m = 0; m < 4; ++m) {
#pragma unroll
        for (int r = 0; r < 4; ++r) {
            float bv = 3.4e38f;
            int bi = 0;
#pragma unroll
            for (int n = 0; n < 4; ++n) {
                float sc = c2v[n] - 2.0f * acc[m][n][r];
                int idx = colbase + n * 16;
                if (sc < bv) { bv = sc; bi = idx; }
            }
#pragma unroll
            for (int off = 1; off < 16; off <<= 1) {
                float ov = __shfl_xor(bv, off);
                int oi = __shfl_xor(bi, off);
                if (ov < bv || (ov == bv && oi < bi)) { bv = ov; bi = oi; }
            }
            if (l15 == 0) {
                unsigned u = __float_as_uint(bv);
                u = (u & 0x80000000u) ? ~u : (u | 0x80000000u);
                kbuf[wc * 128 + wr * 64 + m * 16 + q * 4 + r] =
                    ((unsigned long long)u << 32) | (unsigned)bi;
            }
        }
    }
    __syncthreads();
    if (tid < 128) {
        unsigned long long k = kbuf[tid];
        unsigned long long o = kbuf[128 + tid];
        if (o < k) k = o;
        atomicMin(&keys[trow * 128 + tid], k);
    }
}

// ================= gather + partial loss =================
__global__ __launch_bounds__(256) void gather_keys_kernel(
    const float* __restrict__ x, const float* __restrict__ W,
    const unsigned long long* __restrict__ keys, float* __restrict__ emb_out,
    float* __restrict__ idsf, float* __restrict__ partials) {
    int wid = threadIdx.x >> 6;
    int lane = threadIdx.x & 63;
    int tok = blockIdx.x * 4 + wid;
    int id = (int)(unsigned)(keys[tok] & 0xffffffffull);
    if (lane == 0) idsf[tok] = (float)id;
    const float* wr = W + (size_t)id * DIM;
    const float* xr = x + (size_t)tok * DIM;
    float* orow = emb_out + (size_t)tok * DIM;
    float s = 0.f;
#pragma unroll
    for (int q = 0; q < 2; ++q) {
        int d = q * 256 + lane * 4;
        float4 wv = *(const float4*)(wr + d);
        float4 xv = *(const float4*)(xr + d);
        float4 e = {xv.x + (wv.x - xv.x), xv.y + (wv.y - xv.y),
                    xv.z + (wv.z - xv.z), xv.w + (wv.w - xv.w)};
        *(float4*)(orow + d) = e;
        float dx = xv.x - wv.x, dy = xv.y - wv.y, dz = xv.z - wv.z, dw = xv.w - wv.w;
        s += dx * dx + dy * dy + dz * dz + dw * dw;
    }
#pragma unroll
    for (int off = 32; off > 0; off >>= 1) s += __shfl_down(s, off);
    __shared__ float bsum[4];
    if (lane == 0) bsum[wid] = s;
    __syncthreads();
    if (threadIdx.x == 0)
        partials[blockIdx.x] = bsum[0] + bsum[1] + bsum[2] + bsum[3];
}

// ================= fp32 fallback (ws too small; not expected) =================
#define FBN 64
#define FBK 64
#define FDC 32
#define FPAD 68
__global__ __launch_bounds__(256) void argmin_kernel(const float* __restrict__ x,
                                                     const float* __restrict__ W,
                                                     const float* __restrict__ c2,
                                                     float* __restrict__ idsf) {
    __shared__ float xs[FDC][FPAD];
    __shared__ float wt[FDC][FPAD];
    __shared__ float c2s[FBK];
    __shared__ float redv[16][FBN];
    __shared__ int redi[16][FBN];
    const int tid = threadIdx.x;
    const int n0 = blockIdx.x * FBN;
    const int i = tid & 15;
    const int j = tid >> 4;
    float bestv[4];
    int besti[4];
#pragma unroll
    for (int t = 0; t < 4; ++t) { bestv[t] = 3.4e38f; besti[t] = 0; }
    for (int k0 = 0; k0 < KC; k0 += FBK) {
        __syncthreads();
        if (tid < FBK) c2s[tid] = c2[k0 + tid];
        float acc[4][4];
#pragma unroll
        for (int a = 0; a < 4; ++a)
#pragma unroll
            for (int b = 0; b < 4; ++b) acc[a][b] = 0.f;
        for (int d0 = 0; d0 < DIM; d0 += FDC) {
            __syncthreads();
#pragma unroll
            for (int r = 0; r < 2; ++r) {
                int f = tid + r * 256;
                int tok = f >> 3;
                int dq = f & 7;
                float4 xv = *(const float4*)(x + (size_t)(n0 + tok) * DIM + d0 + dq * 4);
                float4 wv = *(const float4*)(W + (size_t)(k0 + tok) * DIM + d0 + dq * 4);
                xs[dq * 4 + 0][tok] = xv.x; xs[dq * 4 + 1][tok] = xv.y;
                xs[dq * 4 + 2][tok] = xv.z; xs[dq * 4 + 3][tok] = xv.w;
                wt[dq * 4 + 0][tok] = wv.x; wt[dq * 4 + 1][tok] = wv.y;
                wt[dq * 4 + 2][tok] = wv.z; wt[dq * 4 + 3][tok] = wv.w;
            }
            __syncthreads();
#pragma unroll
            for (int d = 0; d < FDC; ++d) {
                float4 xv = *(const float4*)(&xs[d][i * 4]);
                float4 wv = *(const float4*)(&wt[d][j * 4]);
#pragma unroll
                for (int a = 0; a < 4; ++a) {
                    float xa = (a == 0) ? xv.x : (a == 1) ? xv.y : (a == 2) ? xv.z : xv.w;
                    acc[a][0] = fmaf(xa, wv.x, acc[a][0]);
                    acc[a][1] = fmaf(xa, wv.y, acc[a][1]);
                    acc[a][2] = fmaf(xa, wv.z, acc[a][2]);
                    acc[a][3] = fmaf(xa, wv.w, acc[a][3]);
                }
            }
        }
#pragma unroll
        for (int ti = 0; ti < 4; ++ti)
#pragma unroll
            for (int cj = 0; cj < 4; ++cj) {
                float s = c2s[j * 4 + cj] - 2.f * acc[ti][cj];
                int kk = k0 + j * 4 + cj;
                if (s < bestv[ti]) { bestv[ti] = s; besti[ti] = kk; }
            }
    }
#pragma unroll
    for (int ti = 0; ti < 4; ++ti) {
        redv[j][i * 4 + ti] = bestv[ti];
        redi[j][i * 4 + ti] = besti[ti];
    }
    __syncthreads();
    if (tid < FBN) {
        float bv = redv[0][tid];
        int bi = redi[0][tid];
#pragma unroll
        for (int jj = 1; jj < 16; ++jj) {
            float v = redv[jj][tid];
            int ii = redi[jj][tid];
            if (v < bv || (v == bv && ii < bi)) { bv = v; bi = ii; }
        }
        idsf[n0 + tid] = (float)bi;
    }
}

__global__ __launch_bounds__(256) void gather_kernel(const float* __restrict__ x,
                                                     const float* __restrict__ W,
                                                     const float* __restrict__ idsf,
                                                     float* __restrict__ emb_out,
                                                     float* __restrict__ partials) {
    int wid = threadIdx.x >> 6;
    int lane = threadIdx.x & 63;
    int tok = blockIdx.x * 4 + wid;
    int id = (int)idsf[tok];
    const float* wr = W + (size_t)id * DIM;
    const float* xr = x + (size_t)tok * DIM;
    float* orow = emb_out + (size_t)tok * DIM;
    float s = 0.f;
#pragma unroll
    for (int q = 0; q < 2; ++q) {
        int d = q * 256 + lane * 4;
        float4 wv = *(const float4*)(wr + d);
        float4 xv = *(const float4*)(xr + d);
        float4 e = {xv.x + (wv.x - xv.x), xv.y + (wv.y - xv.y),
                    xv.z + (wv.z - xv.z), xv.w + (wv.w - xv.w)};
        *(float4*)(orow + d) = e;
        float dx = xv.x - wv.x, dy = xv.y - wv.y, dz = xv.z - wv.z, dw = xv.w - wv.w;
        s += dx * dx + dy * dy + dz * dz + dw * dw;
    }
#pragma unroll
    for (int off = 32; off > 0; off >>= 1) s += __shfl_down(s, off);
    __shared__ float bsum[4];
    if (lane == 0) bsum[wid] = s;
    __syncthreads();
    if (threadIdx.x == 0)
        partials[blockIdx.x] = bsum[0] + bsum[1] + bsum[2] + bsum[3];
}

// ================= host =================
extern "C" void kernel_launch(void* const* d_in, const int* in_sizes, int n_in,
                              void* d_out, int out_size, void* d_ws, size_t ws_size,
                              hipStream_t stream) {
    const float* x = (const float*)d_in[0];
    const float* W = (const float*)d_in[2];

    float* out = (float*)d_out;
    float* emb_out = out;
    float* idsf = out + (size_t)NTOK * DIM;
    float* lossp = idsf + NTOK;

    const size_t W12_BYTES = (size_t)KC * DIM * 4;  // 16 MB fp16 hi+lo planes
    const size_t KEYS_BYTES = (size_t)NTOK * 8;
    size_t need = W12_BYTES + KEYS_BYTES + (size_t)KC * 4 + (size_t)(NTOK / 4) * 4;

    if (ws_size >= need) {
        u16* w12 = (u16*)d_ws;
        unsigned long long* keys = (unsigned long long*)((char*)d_ws + W12_BYTES);
        float* c2 = (float*)((char*)keys + KEYS_BYTES);
        float* partials = c2 + KC;
        u16* x12 = (u16*)emb_out;  // 64 MB emb region doubles as x-split scratch

        split_kernel<1><<<dim3(NTOK / 64, 4), 256, 0, stream>>>(x, x12);   // swizzled (LDS path)
        split_kernel<0><<<dim3(KC / 64, 4), 256, 0, stream>>>(W, w12);     // linear (reg path)
        c2_kernel<<<KC / 4, 256, 0, stream>>>(W, c2);
        init_keys_kernel<<<NTOK / 256, 256, 0, stream>>>(keys);
        argmin_mfma_kernel<<<(NTOK / TBM) * (KC / TBN), 256, 0, stream>>>(x12, w12, c2, keys);
        gather_keys_kernel<<<NTOK / 4, 256, 0, stream>>>(x, W, keys, emb_out, idsf, partials);
        loss_kernel<<<1, 256, 0, stream>>>(partials, lossp);
    } else {
        float* c2 = (float*)d_ws;
        float* partials = c2 + KC;
        c2_kernel<<<KC / 4, 256, 0, stream>>>(W, c2);
        argmin_kernel<<<NTOK / FBN, 256, 0, stream>>>(x, W, c2, idsf);
        gather_kernel<<<NTOK / 4, 256, 0, stream>>>(x, W, idsf, emb_out, partials);
        loss_kernel<<<1, 256, 0, stream>>>(partials, lossp);
    }
}

// Round 9
// 888.118 us; speedup vs baseline: 7.4005x; 7.4005x over previous
//
#include <hip/hip_runtime.h>
#include <math.h>

#define NTOK 32768
#define DIM 512
#define KC 8192

// ---- MFMA pipeline geometry ----
#define TBM 128              // token tile
#define TBN 128              // code tile
#define HSTEPS 16            // k-chunks (512 / 32)
#define PSTEP 4096           // u16 per plane-chunk per 128-row tile (128 rows x 32 halves = 8 KB)

typedef unsigned short u16;
typedef _Float16 half8 __attribute__((ext_vector_type(8)));
typedef float f32x4 __attribute__((ext_vector_type(4)));

// ---- async global->LDS, 16B per lane (dest = wave-uniform base + lane*16) ----
__device__ __forceinline__ void gload16(const void* g, void* l) {
    __builtin_amdgcn_global_load_lds(
        (const __attribute__((address_space(1))) unsigned int*)(void*)g,
        (__attribute__((address_space(3))) unsigned int*)l, 16, 0, 0);
}

// ================= small kernels =================
__global__ __launch_bounds__(256) void c2_kernel(const float* __restrict__ W,
                                                 float* __restrict__ c2) {
    int wid = threadIdx.x >> 6;
    int lane = threadIdx.x & 63;
    int row = blockIdx.x * 4 + wid;
    const float* wr = W + (size_t)row * DIM;
    float s = 0.f;
#pragma unroll
    for (int q = 0; q < 2; ++q) {
        float4 v = *(const float4*)(wr + q * 256 + lane * 4);
        s += v.x * v.x + v.y * v.y + v.z * v.z + v.w * v.w;
    }
#pragma unroll
    for (int off = 32; off > 0; off >>= 1) s += __shfl_down(s, off);
    if (lane == 0) c2[row] = s;
}

__global__ __launch_bounds__(256) void loss_kernel(const float* __restrict__ partials,
                                                   float* __restrict__ lossp) {
    __shared__ float red[256];
    float s = 0.f;
    for (int idx = threadIdx.x; idx < NTOK / 4; idx += 256) s += partials[idx];
    red[threadIdx.x] = s;
    __syncthreads();
    for (int off = 128; off > 0; off >>= 1) {
        if (threadIdx.x < off) red[threadIdx.x] += red[threadIdx.x + off];
        __syncthreads();
    }
    if (threadIdx.x == 0) lossp[0] = 1.25f * red[0] / (float)NTOK;
}

__global__ void init_keys_kernel(unsigned long long* keys) {
    keys[blockIdx.x * 256 + threadIdx.x] = ~0ull;
}

// ================= split: fp32 -> fp16 hi/lo planes =================
// Per matrix: tiles of 128 rows; per tile 32 plane-steps (0-15 hi, 16-31 lo);
// per step: 128 rows x 32 halves (64 B/row = 4 chunks of 16 B).
// SWZ=1 (x / LDS path): chunk c stored at slot c ^ ((Rl>>1)&3) -> conflict-free
// ds_read_b128 after LINEAR global_load_lds staging.
// SWZ=0 (W / direct-to-register path): linear slots.
template <int SWZ>
__global__ __launch_bounds__(256) void split_kernel(const float* __restrict__ src,
                                                    u16* __restrict__ dst) {
    int lane = threadIdx.x & 63;
    int wid = threadIdx.x >> 6;
    int row = blockIdx.x * 64 + lane;
    int s = blockIdx.y * 4 + wid;          // hi step 0..15
    const float* p = src + (size_t)row * DIM + s * 32;
    int tile = row >> 7, Rl = row & 127, swz = (Rl >> 1) & 3;
    u16* baseH = dst + ((size_t)(tile * 32 + s) * 128 + Rl) * 32;
    u16* baseL = baseH + (size_t)16 * PSTEP;
#pragma unroll
    for (int c = 0; c < 4; ++c) {
        float4 va = ((const float4*)p)[c * 2];
        float4 vb = ((const float4*)p)[c * 2 + 1];
        float f[8] = {va.x, va.y, va.z, va.w, vb.x, vb.y, vb.z, vb.w};
        unsigned H[4], L[4];
#pragma unroll
        for (int j = 0; j < 4; ++j) {
            _Float16 h0 = (_Float16)f[2 * j];
            _Float16 g0 = (_Float16)(f[2 * j] - (float)h0);
            _Float16 h1 = (_Float16)f[2 * j + 1];
            _Float16 g1 = (_Float16)(f[2 * j + 1] - (float)h1);
            H[j] = (unsigned)__builtin_bit_cast(u16, h0) |
                   ((unsigned)__builtin_bit_cast(u16, h1) << 16);
            L[j] = (unsigned)__builtin_bit_cast(u16, g0) |
                   ((unsigned)__builtin_bit_cast(u16, g1) << 16);
        }
        int slot = (SWZ ? (c ^ swz) : c) * 8;
        *(uint4*)(baseH + slot) = uint4{H[0], H[1], H[2], H[3]};
        *(uint4*)(baseL + slot) = uint4{L[0], L[1], L[2], L[3]};
    }
}

// ================= fused GEMM + argmin: A via LDS (32 KB), B direct-to-reg (single-buffered) =================
// 32 KB LDS + ~150 VGPR -> 3 blocks/CU (12 waves/CU). B loads issued FIRST each
// chunk so the compiler's wait for B is vmcnt(4), leaving the A-prefetch in flight.
__global__ __launch_bounds__(256, 3) void argmin_mfma_kernel(
    const u16* __restrict__ xscr, const u16* __restrict__ wscr,
    const float* __restrict__ c2, unsigned long long* __restrict__ keys) {
    __shared__ __align__(16) u16 AH[2][PSTEP];
    __shared__ __align__(16) u16 AL[2][PSTEP];   // total 32 KB

    // XCD-aware swizzle (16384 % 8 == 0 -> bijective)
    int cpx = (int)gridDim.x >> 3;
    int bid = (int)blockIdx.x;
    int wg = (bid & 7) * cpx + (bid >> 3);
    int tcol = wg & 63;    // 64 code tiles of 128
    int trow = wg >> 6;    // 256 token tiles of 128

    const int tid = threadIdx.x;
    const int lane = tid & 63;
    const int w = tid >> 6;
    const int wr = w >> 1;           // M half (64 rows)
    const int wc = w & 1;            // N half (64 cols)

    const u16* gA = xscr + (size_t)trow * (32 * PSTEP);   // [0..15]=hi, [16..31]=lo
    const u16* gB = wscr + (size_t)tcol * (32 * PSTEP);   // linear layout

    const int l15 = lane & 15, q = lane >> 4;
    float c2v[4];
    const int colbase = tcol * 128 + wc * 64 + l15;
#pragma unroll
    for (int n = 0; n < 4; ++n) c2v[n] = c2[colbase + n * 16];

    f32x4 acc[4][4];
#pragma unroll
    for (int m = 0; m < 4; ++m)
#pragma unroll
        for (int n = 0; n < 4; ++n) acc[m][n] = f32x4{0.f, 0.f, 0.f, 0.f};

    // A LDS read offsets (u16 units), conflict-free via pre-swizzled source.
    const int swz = (l15 >> 1) & 3;
    const int soff = (q ^ swz) * 8;
    const int arow = (wr * 64 + l15) * 32;   // + m*512
    // B direct-load offset (linear scratch, u16 units): row*32 + q*8, rows n*16 apart.
    const int boff = (wc * 64 + l15) * 32 + q * 8;
    const int wo = w * 1024;         // wave's 2 KB slice of each 8 KB plane (u16)
    const int lo8 = lane * 8;        // lane's 16 B (global side only)

    // prologue: stage A chunk 0 into buffer 0
    {
        const u16* ah = gA;
        const u16* al = gA + 16 * PSTEP;
        gload16(ah + wo + lo8, AH[0] + wo);
        gload16(ah + wo + 512 + lo8, AH[0] + wo + 512);
        gload16(al + wo + lo8, AL[0] + wo);
        gload16(al + wo + 512 + lo8, AL[0] + wo + 512);
    }

#pragma unroll 2
    for (int c = 0; c < HSTEPS; ++c) {
        const int b = c & 1;
        // chunk c's A staging landed; publish
        asm volatile("s_waitcnt vmcnt(0)" ::: "memory");
        __builtin_amdgcn_s_barrier();
        __builtin_amdgcn_sched_barrier(0);

        // B loads for chunk c FIRST (so waiting on them leaves A-prefetch in flight)
        const u16* bh = gB + (size_t)c * PSTEP;
        const u16* bl = bh + 16 * PSTEP;
        half8 bhv[4], blv[4];
#pragma unroll
        for (int n = 0; n < 4; ++n) {
            bhv[n] = *(const half8*)(bh + boff + n * 512);
            blv[n] = *(const half8*)(bl + boff + n * 512);
        }

        // A-prefetch of chunk c+1 into the other buffer
        if (c + 1 < HSTEPS) {
            const u16* ah = gA + (size_t)(c + 1) * PSTEP;
            const u16* al = ah + 16 * PSTEP;
            u16* dah = AH[b ^ 1];
            u16* dal = AL[b ^ 1];
            gload16(ah + wo + lo8, dah + wo);
            gload16(ah + wo + 512 + lo8, dah + wo + 512);
            gload16(al + wo + lo8, dal + wo);
            gload16(al + wo + 512 + lo8, dal + wo + 512);
        }

        // ---- pass 1: a_hi x b_hi ----
        half8 ahv[4];
#pragma unroll
        for (int m = 0; m < 4; ++m) ahv[m] = *(const half8*)(AH[b] + arow + m * 512 + soff);
        __builtin_amdgcn_s_setprio(1);
#pragma unroll
        for (int m = 0; m < 4; ++m)
#pragma unroll
            for (int n = 0; n < 4; ++n)
                acc[m][n] = __builtin_amdgcn_mfma_f32_16x16x32_f16(ahv[m], bhv[n], acc[m][n], 0, 0, 0);
        __builtin_amdgcn_s_setprio(0);

        // ---- pass 2: a_lo x b_hi ----
        half8 alv[4];
#pragma unroll
        for (int m = 0; m < 4; ++m) alv[m] = *(const half8*)(AL[b] + arow + m * 512 + soff);
        __builtin_amdgcn_s_setprio(1);
#pragma unroll
        for (int m = 0; m < 4; ++m)
#pragma unroll
            for (int n = 0; n < 4; ++n)
                acc[m][n] = __builtin_amdgcn_mfma_f32_16x16x32_f16(alv[m], bhv[n], acc[m][n], 0, 0, 0);

        // ---- pass 3: a_hi x b_lo ----
#pragma unroll
        for (int m = 0; m < 4; ++m)
#pragma unroll
            for (int n = 0; n < 4; ++n)
                acc[m][n] = __builtin_amdgcn_mfma_f32_16x16x32_f16(ahv[m], blv[n], acc[m][n], 0, 0, 0);
        __builtin_amdgcn_s_setprio(0);
    }

    // ---- epilogue: scores + argmin; block-level key reduce in LDS ----
    unsigned long long* kbuf = (unsigned long long*)&AH[0][0];  // buffers dead
#pragma unroll
    for (int m = 0; m < 4; ++m) {
#pragma unroll
        for (int r = 0; r < 4; ++r) {
            float bv = 3.4e38f;
            int bi = 0;
#pragma unroll
            for (int n = 0; n < 4; ++n) {
                float sc = c2v[n] - 2.0f * acc[m][n][r];
                int idx = colbase + n * 16;
                if (sc < bv) { bv = sc; bi = idx; }
            }
#pragma unroll
            for (int off = 1; off < 16; off <<= 1) {
                float ov = __shfl_xor(bv, off);
                int oi = __shfl_xor(bi, off);
                if (ov < bv || (ov == bv && oi < bi)) { bv = ov; bi = oi; }
            }
            if (l15 == 0) {
                unsigned u = __float_as_uint(bv);
                u = (u & 0x80000000u) ? ~u : (u | 0x80000000u);
                kbuf[wc * 128 + wr * 64 + m * 16 + q * 4 + r] =
                    ((unsigned long long)u << 32) | (unsigned)bi;
            }
        }
    }
    __syncthreads();
    if (tid < 128) {
        unsigned long long k = kbuf[tid];
        unsigned long long o = kbuf[128 + tid];
        if (o < k) k = o;
        atomicMin(&keys[trow * 128 + tid], k);
    }
}

// ================= gather + partial loss =================
__global__ __launch_bounds__(256) void gather_keys_kernel(
    const float* __restrict__ x, const float* __restrict__ W,
    const unsigned long long* __restrict__ keys, float* __restrict__ emb_out,
    float* __restrict__ idsf, float* __restrict__ partials) {
    int wid = threadIdx.x >> 6;
    int lane = threadIdx.x & 63;
    int tok = blockIdx.x * 4 + wid;
    int id = (int)(unsigned)(keys[tok] & 0xffffffffull);
    if (lane == 0) idsf[tok] = (float)id;
    const float* wr = W + (size_t)id * DIM;
    const float* xr = x + (size_t)tok * DIM;
    float* orow = emb_out + (size_t)tok * DIM;
    float s = 0.f;
#pragma unroll
    for (int q = 0; q < 2; ++q) {
        int d = q * 256 + lane * 4;
        float4 wv = *(const float4*)(wr + d);
        float4 xv = *(const float4*)(xr + d);
        float4 e = {xv.x + (wv.x - xv.x), xv.y + (wv.y - xv.y),
                    xv.z + (wv.z - xv.z), xv.w + (wv.w - xv.w)};
        *(float4*)(orow + d) = e;
        float dx = xv.x - wv.x, dy = xv.y - wv.y, dz = xv.z - wv.z, dw = xv.w - wv.w;
        s += dx * dx + dy * dy + dz * dz + dw * dw;
    }
#pragma unroll
    for (int off = 32; off > 0; off >>= 1) s += __shfl_down(s, off);
    __shared__ float bsum[4];
    if (lane == 0) bsum[wid] = s;
    __syncthreads();
    if (threadIdx.x == 0)
        partials[blockIdx.x] = bsum[0] + bsum[1] + bsum[2] + bsum[3];
}

// ================= fp32 fallback (ws too small; not expected) =================
#define FBN 64
#define FBK 64
#define FDC 32
#define FPAD 68
__global__ __launch_bounds__(256) void argmin_kernel(const float* __restrict__ x,
                                                     const float* __restrict__ W,
                                                     const float* __restrict__ c2,
                                                     float* __restrict__ idsf) {
    __shared__ float xs[FDC][FPAD];
    __shared__ float wt[FDC][FPAD];
    __shared__ float c2s[FBK];
    __shared__ float redv[16][FBN];
    __shared__ int redi[16][FBN];
    const int tid = threadIdx.x;
    const int n0 = blockIdx.x * FBN;
    const int i = tid & 15;
    const int j = tid >> 4;
    float bestv[4];
    int besti[4];
#pragma unroll
    for (int t = 0; t < 4; ++t) { bestv[t] = 3.4e38f; besti[t] = 0; }
    for (int k0 = 0; k0 < KC; k0 += FBK) {
        __syncthreads();
        if (tid < FBK) c2s[tid] = c2[k0 + tid];
        float acc[4][4];
#pragma unroll
        for (int a = 0; a < 4; ++a)
#pragma unroll
            for (int b = 0; b < 4; ++b) acc[a][b] = 0.f;
        for (int d0 = 0; d0 < DIM; d0 += FDC) {
            __syncthreads();
#pragma unroll
            for (int r = 0; r < 2; ++r) {
                int f = tid + r * 256;
                int tok = f >> 3;
                int dq = f & 7;
                float4 xv = *(const float4*)(x + (size_t)(n0 + tok) * DIM + d0 + dq * 4);
                float4 wv = *(const float4*)(W + (size_t)(k0 + tok) * DIM + d0 + dq * 4);
                xs[dq * 4 + 0][tok] = xv.x; xs[dq * 4 + 1][tok] = xv.y;
                xs[dq * 4 + 2][tok] = xv.z; xs[dq * 4 + 3][tok] = xv.w;
                wt[dq * 4 + 0][tok] = wv.x; wt[dq * 4 + 1][tok] = wv.y;
                wt[dq * 4 + 2][tok] = wv.z; wt[dq * 4 + 3][tok] = wv.w;
            }
            __syncthreads();
#pragma unroll
            for (int d = 0; d < FDC; ++d) {
                float4 xv = *(const float4*)(&xs[d][i * 4]);
                float4 wv = *(const float4*)(&wt[d][j * 4]);
#pragma unroll
                for (int a = 0; a < 4; ++a) {
                    float xa = (a == 0) ? xv.x : (a == 1) ? xv.y : (a == 2) ? xv.z : xv.w;
                    acc[a][0] = fmaf(xa, wv.x, acc[a][0]);
                    acc[a][1] = fmaf(xa, wv.y, acc[a][1]);
                    acc[a][2] = fmaf(xa, wv.z, acc[a][2]);
                    acc[a][3] = fmaf(xa, wv.w, acc[a][3]);
                }
            }
        }
#pragma unroll
        for (int ti = 0; ti < 4; ++ti)
#pragma unroll
            for (int cj = 0; cj < 4; ++cj) {
                float s = c2s[j * 4 + cj] - 2.f * acc[ti][cj];
                int kk = k0 + j * 4 + cj;
                if (s < bestv[ti]) { bestv[ti] = s; besti[ti] = kk; }
            }
    }
#pragma unroll
    for (int ti = 0; ti < 4; ++ti) {
        redv[j][i * 4 + ti] = bestv[ti];
        redi[j][i * 4 + ti] = besti[ti];
    }
    __syncthreads();
    if (tid < FBN) {
        float bv = redv[0][tid];
        int bi = redi[0][tid];
#pragma unroll
        for (int jj = 1; jj < 16; ++jj) {
            float v = redv[jj][tid];
            int ii = redi[jj][tid];
            if (v < bv || (v == bv && ii < bi)) { bv = v; bi = ii; }
        }
        idsf[n0 + tid] = (float)bi;
    }
}

__global__ __launch_bounds__(256) void gather_kernel(const float* __restrict__ x,
                                                     const float* __restrict__ W,
                                                     const float* __restrict__ idsf,
                                                     float* __restrict__ emb_out,
                                                     float* __restrict__ partials) {
    int wid = threadIdx.x >> 6;
    int lane = threadIdx.x & 63;
    int tok = blockIdx.x * 4 + wid;
    int id = (int)idsf[tok];
    const float* wr = W + (size_t)id * DIM;
    const float* xr = x + (size_t)tok * DIM;
    float* orow = emb_out + (size_t)tok * DIM;
    float s = 0.f;
#pragma unroll
    for (int q = 0; q < 2; ++q) {
        int d = q * 256 + lane * 4;
        float4 wv = *(const float4*)(wr + d);
        float4 xv = *(const float4*)(xr + d);
        float4 e = {xv.x + (wv.x - xv.x), xv.y + (wv.y - xv.y),
                    xv.z + (wv.z - xv.z), xv.w + (wv.w - xv.w)};
        *(float4*)(orow + d) = e;
        float dx = xv.x - wv.x, dy = xv.y - wv.y, dz = xv.z - wv.z, dw = xv.w - wv.w;
        s += dx * dx + dy * dy + dz * dz + dw * dw;
    }
#pragma unroll
    for (int off = 32; off > 0; off >>= 1) s += __shfl_down(s, off);
    __shared__ float bsum[4];
    if (lane == 0) bsum[wid] = s;
    __syncthreads();
    if (threadIdx.x == 0)
        partials[blockIdx.x] = bsum[0] + bsum[1] + bsum[2] + bsum[3];
}

// ================= host =================
extern "C" void kernel_launch(void* const* d_in, const int* in_sizes, int n_in,
                              void* d_out, int out_size, void* d_ws, size_t ws_size,
                              hipStream_t stream) {
    const float* x = (const float*)d_in[0];
    const float* W = (const float*)d_in[2];

    float* out = (float*)d_out;
    float* emb_out = out;
    float* idsf = out + (size_t)NTOK * DIM;
    float* lossp = idsf + NTOK;

    const size_t W12_BYTES = (size_t)KC * DIM * 4;  // 16 MB fp16 hi+lo planes
    const size_t KEYS_BYTES = (size_t)NTOK * 8;
    size_t need = W12_BYTES + KEYS_BYTES + (size_t)KC * 4 + (size_t)(NTOK / 4) * 4;

    if (ws_size >= need) {
        u16* w12 = (u16*)d_ws;
        unsigned long long* keys = (unsigned long long*)((char*)d_ws + W12_BYTES);
        float* c2 = (float*)((char*)keys + KEYS_BYTES);
        float* partials = c2 + KC;
        u16* x12 = (u16*)emb_out;  // 64 MB emb region doubles as x-split scratch

        split_kernel<1><<<dim3(NTOK / 64, 4), 256, 0, stream>>>(x, x12);   // swizzled (LDS path)
        split_kernel<0><<<dim3(KC / 64, 4), 256, 0, stream>>>(W, w12);     // linear (reg path)
        c2_kernel<<<KC / 4, 256, 0, stream>>>(W, c2);
        init_keys_kernel<<<NTOK / 256, 256, 0, stream>>>(keys);
        argmin_mfma_kernel<<<(NTOK / TBM) * (KC / TBN), 256, 0, stream>>>(x12, w12, c2, keys);
        gather_keys_kernel<<<NTOK / 4, 256, 0, stream>>>(x, W, keys, emb_out, idsf, partials);
        loss_kernel<<<1, 256, 0, stream>>>(partials, lossp);
    } else {
        float* c2 = (float*)d_ws;
        float* partials = c2 + KC;
        c2_kernel<<<KC / 4, 256, 0, stream>>>(W, c2);
        argmin_kernel<<<NTOK / FBN, 256, 0, stream>>>(x, W, c2, idsf);
        gather_kernel<<<NTOK / 4, 256, 0, stream>>>(x, W, idsf, emb_out, partials);
        loss_kernel<<<1, 256, 0, stream>>>(partials, lossp);
    }
}